// Round 1
// baseline (759.539 us; speedup 1.0000x reference)
//
#include <hip/hip_runtime.h>

#define HID   15
#define TMAIN 1024
#define FUT   64
#define OUTW  (TMAIN + FUT)   // 1088

// sigmoid(x) = 1/(1+exp2(-x*log2(e))) ; tanh(x) = 2/(1+exp2(-2x*log2(e))) - 1
__device__ __forceinline__ float sigm(float x) {
    float e = __builtin_amdgcn_exp2f(x * -1.442695040888963f);
    return __builtin_amdgcn_rcpf(1.0f + e);
}
__device__ __forceinline__ float tanh_(float x) {
    float e = __builtin_amdgcn_exp2f(x * -2.885390081777927f);
    return __builtin_fmaf(2.0f, __builtin_amdgcn_rcpf(1.0f + e), -1.0f);
}

// Mapping: 1 wave = 4 batch elements. lane = g*16 + k, g = batch subgroup (0..3),
// k = hidden unit (0..14; k==15 is a zero-weight pad lane). Each lane computes all
// 4 gates of its unit in-lane (no cross-lane gate combine). h broadcast per layer:
// 1 ds_write + 4 ds_read_b128 from a per-(wave,group) 16-float LDS slot.
// Occupancy is structurally 1 wave/SIMD (1024 waves), so VGPR use up to 512 is free.
__global__ __launch_bounds__(256, 1)
void lstm_seq_kernel(const float* __restrict__ input,
                     const float* __restrict__ W_ih1, const float* __restrict__ W_hh1,
                     const float* __restrict__ b_ih1, const float* __restrict__ b_hh1,
                     const float* __restrict__ W_ih2, const float* __restrict__ W_hh2,
                     const float* __restrict__ b_ih2, const float* __restrict__ b_hh2,
                     const float* __restrict__ W_lin, const float* __restrict__ b_lin,
                     float* __restrict__ out)
{
    __shared__ float xs [4][4][64];   // per-wave staged input tile [wave][batch][t]
    __shared__ float os [4][4][64];   // per-wave output tile
    __shared__ float h1s[4][4][16];   // h1 broadcast slots [wave][group][unit]
    __shared__ float h2s[4][4][16];

    const int tid  = threadIdx.x;
    const int wq   = tid >> 6;        // wave in block
    const int lane = tid & 63;
    const int g    = lane >> 4;       // batch subgroup
    const int k    = lane & 15;       // hidden unit (15 = pad)
    const int b0   = (blockIdx.x * 4 + wq) * 4;   // first batch of this wave

    const bool pad = (k >= HID);
    const float m  = pad ? 0.0f : 1.0f;
    const int  kk  = pad ? 0 : k;

    // Per-lane weight rows (gate order i,f,g,o -> rows gi*15+k). Zeroed on pad lane
    // so its h stays finite 0 (0*NaN would poison the output butterfly otherwise).
    float w1[4][HID], w2i[4][HID], w2h[4][HID];
    float wih1[4], bb1[4], bb2[4];
    #pragma unroll
    for (int gi = 0; gi < 4; ++gi) {
        const int row = gi * HID + kk;
        wih1[gi] = m * W_ih1[row];
        bb1[gi]  = m * (b_ih1[row] + b_hh1[row]);
        bb2[gi]  = m * (b_ih2[row] + b_hh2[row]);
        #pragma unroll
        for (int c = 0; c < HID; ++c) {
            w1 [gi][c] = m * W_hh1[row * HID + c];
            w2i[gi][c] = m * W_ih2[row * HID + c];
            w2h[gi][c] = m * W_hh2[row * HID + c];
        }
    }
    const float wlin = m * W_lin[kk];
    const float blin = b_lin[0];

    float h1x[16], h2x[16];           // replicated h vectors (refreshed from LDS)
    #pragma unroll
    for (int i = 0; i < 16; ++i) { h1x[i] = 0.0f; h2x[i] = 0.0f; }
    float c1 = 0.0f, c2 = 0.0f;
    float outv = 0.0f;

    auto step = [&](float x, int c) {
        // ---- layer 1 gates (uses previous h1x) ----
        float a0 = __builtin_fmaf(wih1[0], x, bb1[0]);
        float a1 = __builtin_fmaf(wih1[1], x, bb1[1]);
        float a2 = __builtin_fmaf(wih1[2], x, bb1[2]);
        float a3 = __builtin_fmaf(wih1[3], x, bb1[3]);
        #pragma unroll
        for (int j = 0; j < HID; ++j) {
            const float hv = h1x[j];
            a0 = __builtin_fmaf(w1[0][j], hv, a0);
            a1 = __builtin_fmaf(w1[1][j], hv, a1);
            a2 = __builtin_fmaf(w1[2][j], hv, a2);
            a3 = __builtin_fmaf(w1[3][j], hv, a3);
        }
        const float ig = sigm(a0), fg = sigm(a1), gg = tanh_(a2), og = sigm(a3);
        c1 = __builtin_fmaf(fg, c1, ig * gg);
        const float h1n = og * tanh_(c1);

        // share h1 (issue reads early; L2-hh below is independent and covers latency)
        h1s[wq][g][k] = h1n;
        const float4 q0 = *(const float4*)&h1s[wq][g][0];
        const float4 q1 = *(const float4*)&h1s[wq][g][4];
        const float4 q2 = *(const float4*)&h1s[wq][g][8];
        const float4 q3 = *(const float4*)&h1s[wq][g][12];

        // ---- layer 2: hh part first (uses previous h2x, hides h1 LDS round-trip)
        float d0 = bb2[0], d1 = bb2[1], d2 = bb2[2], d3 = bb2[3];
        #pragma unroll
        for (int j = 0; j < HID; ++j) {
            const float hv = h2x[j];
            d0 = __builtin_fmaf(w2h[0][j], hv, d0);
            d1 = __builtin_fmaf(w2h[1][j], hv, d1);
            d2 = __builtin_fmaf(w2h[2][j], hv, d2);
            d3 = __builtin_fmaf(w2h[3][j], hv, d3);
        }
        // refresh h1x from LDS reads
        h1x[0]=q0.x;  h1x[1]=q0.y;  h1x[2]=q0.z;  h1x[3]=q0.w;
        h1x[4]=q1.x;  h1x[5]=q1.y;  h1x[6]=q1.z;  h1x[7]=q1.w;
        h1x[8]=q2.x;  h1x[9]=q2.y;  h1x[10]=q2.z; h1x[11]=q2.w;
        h1x[12]=q3.x; h1x[13]=q3.y; h1x[14]=q3.z; h1x[15]=q3.w;
        #pragma unroll
        for (int j = 0; j < HID; ++j) {
            const float hv = h1x[j];
            d0 = __builtin_fmaf(w2i[0][j], hv, d0);
            d1 = __builtin_fmaf(w2i[1][j], hv, d1);
            d2 = __builtin_fmaf(w2i[2][j], hv, d2);
            d3 = __builtin_fmaf(w2i[3][j], hv, d3);
        }
        const float i2 = sigm(d0), f2 = sigm(d1), g2 = tanh_(d2), o2 = sigm(d3);
        c2 = __builtin_fmaf(f2, c2, i2 * g2);
        const float h2n = o2 * tanh_(c2);

        // out = sum_k Wlin[k]*h2[k] + blin via 16-lane xor butterfly (in-lane result
        // feeds the autoregressive future phase with no extra data movement)
        float p = h2n * wlin;
        p += __shfl_xor(p, 1);
        p += __shfl_xor(p, 2);
        p += __shfl_xor(p, 4);
        p += __shfl_xor(p, 8);
        const float ov = p + blin;
        os[wq][g][c] = ov;            // 16 lanes, same addr, same value: OK

        // share h2 for next step (latency hidden by next step's layer-1 work)
        h2s[wq][g][k] = h2n;
        const float4 r0 = *(const float4*)&h2s[wq][g][0];
        const float4 r1 = *(const float4*)&h2s[wq][g][4];
        const float4 r2 = *(const float4*)&h2s[wq][g][8];
        const float4 r3 = *(const float4*)&h2s[wq][g][12];
        h2x[0]=r0.x;  h2x[1]=r0.y;  h2x[2]=r0.z;  h2x[3]=r0.w;
        h2x[4]=r1.x;  h2x[5]=r1.y;  h2x[6]=r1.z;  h2x[7]=r1.w;
        h2x[8]=r2.x;  h2x[9]=r2.y;  h2x[10]=r2.z; h2x[11]=r2.w;
        h2x[12]=r3.x; h2x[13]=r3.y; h2x[14]=r3.z; h2x[15]=r3.w;

        outv = ov;
    };

    // ---- main T steps, in tiles of 64 ----
    #pragma unroll 1
    for (int tile = 0; tile < TMAIN / 64; ++tile) {
        const int t0 = tile * 64;
        #pragma unroll
        for (int j = 0; j < 4; ++j)
            xs[wq][j][lane] = input[(size_t)(b0 + j) * TMAIN + t0 + lane];
        #pragma unroll 2
        for (int c = 0; c < 64; ++c)
            step(xs[wq][g][c], c);
        #pragma unroll
        for (int j = 0; j < 4; ++j)
            out[(size_t)(b0 + j) * OUTW + t0 + lane] = os[wq][j][lane];
    }

    // ---- autoregressive future steps: x = previous out (already in-lane) ----
    #pragma unroll 2
    for (int c = 0; c < FUT; ++c)
        step(outv, c);
    #pragma unroll
    for (int j = 0; j < 4; ++j)
        out[(size_t)(b0 + j) * OUTW + TMAIN + lane] = os[wq][j][lane];
}

extern "C" void kernel_launch(void* const* d_in, const int* in_sizes, int n_in,
                              void* d_out, int out_size, void* d_ws, size_t ws_size,
                              hipStream_t stream)
{
    const float* input = (const float*)d_in[0];
    const float* W_ih1 = (const float*)d_in[1];
    const float* W_hh1 = (const float*)d_in[2];
    const float* b_ih1 = (const float*)d_in[3];
    const float* b_hh1 = (const float*)d_in[4];
    const float* W_ih2 = (const float*)d_in[5];
    const float* W_hh2 = (const float*)d_in[6];
    const float* b_ih2 = (const float*)d_in[7];
    const float* b_hh2 = (const float*)d_in[8];
    const float* W_lin = (const float*)d_in[9];
    const float* b_lin = (const float*)d_in[10];
    // d_in[11] = future (=64), compiled in as FUT

    // 4096 batches / (4 per wave * 4 waves per block) = 256 blocks
    lstm_seq_kernel<<<256, 256, 0, stream>>>(
        input, W_ih1, W_hh1, b_ih1, b_hh1,
        W_ih2, W_hh2, b_ih2, b_hh2, W_lin, b_lin,
        (float*)d_out);
}

// Round 2
// 733.893 us; speedup vs baseline: 1.0349x; 1.0349x over previous
//
#include <hip/hip_runtime.h>

#define HID   15
#define TMAIN 1024
#define FUT   64
#define OUTW  (TMAIN + FUT)   // 1088

// sigmoid(x) = 1/(1+exp2(-x*log2(e))) ; tanh(x) = 2/(1+exp2(-2x*log2(e))) - 1
__device__ __forceinline__ float sigm(float x) {
    float e = __builtin_amdgcn_exp2f(x * -1.442695040888963f);
    return __builtin_amdgcn_rcpf(1.0f + e);
}
__device__ __forceinline__ float tanh_(float x) {
    float e = __builtin_amdgcn_exp2f(x * -2.885390081777927f);
    return __builtin_fmaf(2.0f, __builtin_amdgcn_rcpf(1.0f + e), -1.0f);
}

// Mapping: 1 wave = 4 batch elements. lane = g*16 + k, g = batch subgroup (0..3),
// k = hidden unit (0..14; k==15 is a zero-weight pad lane). Each lane computes all
// 4 gates of its unit in-lane. h broadcast per layer: 1 ds_write + 4 ds_read_b128.
// W_lin is replicated fully per lane, so `out` is an in-lane dot after the h2
// refresh — no cross-lane butterfly anywhere (R1 showed the 4-deep ds_swizzle
// chain stalled every step).
// waves_per_eu(1,1): grid is exactly 1024 waves = 1/SIMD, so occupancy >1 is
// impossible — let the allocator use the full arch-VGPR file (R1: 136 VGPRs ->
// ~100 weights lived in AGPRs, paying v_accvgpr_read per use per step).
__global__ __launch_bounds__(256)
__attribute__((amdgpu_waves_per_eu(1, 1)))
void lstm_seq_kernel(const float* __restrict__ input,
                     const float* __restrict__ W_ih1, const float* __restrict__ W_hh1,
                     const float* __restrict__ b_ih1, const float* __restrict__ b_hh1,
                     const float* __restrict__ W_ih2, const float* __restrict__ W_hh2,
                     const float* __restrict__ b_ih2, const float* __restrict__ b_hh2,
                     const float* __restrict__ W_lin, const float* __restrict__ b_lin,
                     float* __restrict__ out)
{
    __shared__ float xs [4][4][64];   // per-wave staged input tile [wave][batch][t]
    __shared__ float os [4][4][64];   // per-wave output tile
    __shared__ float h1s[4][4][16];   // h broadcast slots [wave][group][unit]
    __shared__ float h2s[4][4][16];

    const int tid  = threadIdx.x;
    const int wq   = tid >> 6;        // wave in block
    const int lane = tid & 63;
    const int g    = lane >> 4;       // batch subgroup
    const int k    = lane & 15;       // hidden unit (15 = pad)
    const int b0   = (blockIdx.x * 4 + wq) * 4;   // first batch of this wave

    const bool pad = (k >= HID);
    const float m  = pad ? 0.0f : 1.0f;
    const int  kk  = pad ? 0 : k;

    // Per-lane weight rows (gate order i,f,g,o -> rows gi*15+k). Zeroed on pad
    // lane so its h stays exactly 0 through the recurrence.
    float w1[4][HID], w2i[4][HID], w2h[4][HID];
    float wih1[4], bb1[4], bb2[4];
    #pragma unroll
    for (int gi = 0; gi < 4; ++gi) {
        const int row = gi * HID + kk;
        wih1[gi] = m * W_ih1[row];
        bb1[gi]  = m * (b_ih1[row] + b_hh1[row]);
        bb2[gi]  = m * (b_ih2[row] + b_hh2[row]);
        #pragma unroll
        for (int c = 0; c < HID; ++c) {
            w1 [gi][c] = m * W_hh1[row * HID + c];
            w2i[gi][c] = m * W_ih2[row * HID + c];
            w2h[gi][c] = m * W_hh2[row * HID + c];
        }
    }
    // Full W_lin vector in every lane (in-lane output dot; kills the butterfly)
    float wlin[16];
    #pragma unroll
    for (int j = 0; j < HID; ++j) wlin[j] = W_lin[j];
    wlin[15] = 0.0f;
    const float blin = b_lin[0];

    float h1x[16], h2x[16];           // replicated h vectors (refreshed from LDS)
    #pragma unroll
    for (int i = 0; i < 16; ++i) { h1x[i] = 0.0f; h2x[i] = 0.0f; }
    float c1 = 0.0f, c2 = 0.0f;
    float outv = 0.0f;

    auto step = [&](float x, int c) {
        // ---- layer 1 gates (uses previous h1x) ----
        float a0 = __builtin_fmaf(wih1[0], x, bb1[0]);
        float a1 = __builtin_fmaf(wih1[1], x, bb1[1]);
        float a2 = __builtin_fmaf(wih1[2], x, bb1[2]);
        float a3 = __builtin_fmaf(wih1[3], x, bb1[3]);
        #pragma unroll
        for (int j = 0; j < HID; ++j) {
            const float hv = h1x[j];
            a0 = __builtin_fmaf(w1[0][j], hv, a0);
            a1 = __builtin_fmaf(w1[1][j], hv, a1);
            a2 = __builtin_fmaf(w1[2][j], hv, a2);
            a3 = __builtin_fmaf(w1[3][j], hv, a3);
        }
        const float ig = sigm(a0), fg = sigm(a1), gg = tanh_(a2), og = sigm(a3);
        c1 = __builtin_fmaf(fg, c1, ig * gg);
        const float h1n = og * tanh_(c1);

        // share h1 (issue reads early; L2-hh below is independent, covers latency)
        h1s[wq][g][k] = h1n;
        const float4 q0 = *(const float4*)&h1s[wq][g][0];
        const float4 q1 = *(const float4*)&h1s[wq][g][4];
        const float4 q2 = *(const float4*)&h1s[wq][g][8];
        const float4 q3 = *(const float4*)&h1s[wq][g][12];

        // ---- layer 2: hh part first (uses previous h2x, hides h1 round-trip)
        float d0 = bb2[0], d1 = bb2[1], d2 = bb2[2], d3 = bb2[3];
        #pragma unroll
        for (int j = 0; j < HID; ++j) {
            const float hv = h2x[j];
            d0 = __builtin_fmaf(w2h[0][j], hv, d0);
            d1 = __builtin_fmaf(w2h[1][j], hv, d1);
            d2 = __builtin_fmaf(w2h[2][j], hv, d2);
            d3 = __builtin_fmaf(w2h[3][j], hv, d3);
        }
        h1x[0]=q0.x;  h1x[1]=q0.y;  h1x[2]=q0.z;  h1x[3]=q0.w;
        h1x[4]=q1.x;  h1x[5]=q1.y;  h1x[6]=q1.z;  h1x[7]=q1.w;
        h1x[8]=q2.x;  h1x[9]=q2.y;  h1x[10]=q2.z; h1x[11]=q2.w;
        h1x[12]=q3.x; h1x[13]=q3.y; h1x[14]=q3.z; h1x[15]=q3.w;
        #pragma unroll
        for (int j = 0; j < HID; ++j) {
            const float hv = h1x[j];
            d0 = __builtin_fmaf(w2i[0][j], hv, d0);
            d1 = __builtin_fmaf(w2i[1][j], hv, d1);
            d2 = __builtin_fmaf(w2i[2][j], hv, d2);
            d3 = __builtin_fmaf(w2i[3][j], hv, d3);
        }
        const float i2 = sigm(d0), f2 = sigm(d1), g2 = tanh_(d2), o2 = sigm(d3);
        c2 = __builtin_fmaf(f2, c2, i2 * g2);
        const float h2n = o2 * tanh_(c2);

        // share h2 for next step (latency hidden by next step's layer-1 work)
        h2s[wq][g][k] = h2n;
        const float4 r0 = *(const float4*)&h2s[wq][g][0];
        const float4 r1 = *(const float4*)&h2s[wq][g][4];
        const float4 r2 = *(const float4*)&h2s[wq][g][8];
        const float4 r3 = *(const float4*)&h2s[wq][g][12];
        h2x[0]=r0.x;  h2x[1]=r0.y;  h2x[2]=r0.z;  h2x[3]=r0.w;
        h2x[4]=r1.x;  h2x[5]=r1.y;  h2x[6]=r1.z;  h2x[7]=r1.w;
        h2x[8]=r2.x;  h2x[9]=r2.y;  h2x[10]=r2.z; h2x[11]=r2.w;
        h2x[12]=r3.x; h2x[13]=r3.y; h2x[14]=r3.z; h2x[15]=r3.w;

        // out = <wlin, h2> + blin, in-lane, 4-way tree (short dep chain for the
        // autoregressive future phase where ov feeds the next x)
        float s0 = wlin[0] * h2x[0];
        float s1 = wlin[1] * h2x[1];
        float s2 = wlin[2] * h2x[2];
        float s3 = wlin[3] * h2x[3];
        #pragma unroll
        for (int j = 4; j < 16; j += 4) {
            s0 = __builtin_fmaf(wlin[j+0], h2x[j+0], s0);
            s1 = __builtin_fmaf(wlin[j+1], h2x[j+1], s1);
            s2 = __builtin_fmaf(wlin[j+2], h2x[j+2], s2);
            s3 = __builtin_fmaf(wlin[j+3], h2x[j+3], s3);
        }
        const float ov = (s0 + s1) + (s2 + s3) + blin;
        os[wq][g][c] = ov;            // 16 lanes, same addr, same value: OK
        outv = ov;
    };

    // ---- main T steps, in tiles of 64 ----
    #pragma unroll 1
    for (int tile = 0; tile < TMAIN / 64; ++tile) {
        const int t0 = tile * 64;
        #pragma unroll
        for (int j = 0; j < 4; ++j)
            xs[wq][j][lane] = input[(size_t)(b0 + j) * TMAIN + t0 + lane];
        #pragma unroll 2
        for (int c = 0; c < 64; ++c)
            step(xs[wq][g][c], c);
        #pragma unroll
        for (int j = 0; j < 4; ++j)
            out[(size_t)(b0 + j) * OUTW + t0 + lane] = os[wq][j][lane];
    }

    // ---- autoregressive future steps: x = previous out (already in-lane) ----
    #pragma unroll 1
    for (int c = 0; c < FUT; ++c)
        step(outv, c);
    #pragma unroll
    for (int j = 0; j < 4; ++j)
        out[(size_t)(b0 + j) * OUTW + TMAIN + lane] = os[wq][j][lane];
}

extern "C" void kernel_launch(void* const* d_in, const int* in_sizes, int n_in,
                              void* d_out, int out_size, void* d_ws, size_t ws_size,
                              hipStream_t stream)
{
    const float* input = (const float*)d_in[0];
    const float* W_ih1 = (const float*)d_in[1];
    const float* W_hh1 = (const float*)d_in[2];
    const float* b_ih1 = (const float*)d_in[3];
    const float* b_hh1 = (const float*)d_in[4];
    const float* W_ih2 = (const float*)d_in[5];
    const float* W_hh2 = (const float*)d_in[6];
    const float* b_ih2 = (const float*)d_in[7];
    const float* b_hh2 = (const float*)d_in[8];
    const float* W_lin = (const float*)d_in[9];
    const float* b_lin = (const float*)d_in[10];
    // d_in[11] = future (=64), compiled in as FUT

    // 4096 batches / (4 per wave * 4 waves per block) = 256 blocks
    lstm_seq_kernel<<<256, 256, 0, stream>>>(
        input, W_ih1, W_hh1, b_ih1, b_hh1,
        W_ih2, W_hh2, b_ih2, b_hh2, W_lin, b_lin,
        (float*)d_out);
}